// Round 4
// baseline (95.672 us; speedup 1.0000x reference)
//
#include <hip/hip_runtime.h>

// B=2, N=1024, Fin=64, Fout=32 — all fp32.
// Degenerate-score GAT — SINGLE kernel, ZERO inter-block dependencies
// (round-9: algebraic fusion).
// Key identities (all verified against the passing r3 analytic form):
//  (1) sum-swap:  S_j c_j·vv[j][f] = S_c (S_j c_j·v[j][c])·Wv[c][f]
//      -> main loop runs on RAW v input; Wv applied to the 64-vector g at
//         the end. vv/k_proj eliminated entirely.
//  (2) dot-fold:  p[r] = inp[r]·(W@(a1+a2)); q1[r]=k[r]·(Wk@a1);
//      q2[r]=k[r]·(Wk@a2)  — 64 FMA/row, computed per block.
//  (3) e-period:  e[j] = exp(leaky(q1[(2j)%1024]+q2[(2j+1)%1024])) has
//      period 512 in j (2j mod 1024) -> stage 512 e's, Z = 2*sum.
//  coeff: c^i_j = adj[i][j] + (hi: e[j]*invZ | lo: e{0,1}^i/(512(e0+e1)))
// NOTE (round-1 lesson, measured): sync-based fusion (flag-spin or coop
// grid.sync) costs ~50-65us on this device. THIS fusion has no sync —
// every block computes its own coefficients from raw inputs.
// Budget model (r0-r3): fill ~41us fixed + ~8-12us per node boundary +
// small kernel bodies. This round removes one node + one boundary.

#define ALPHA 0.01f

__device__ __forceinline__ float leaky(float x){ return x >= 0.f ? x : ALPHA*x; }

// 512 blocks x 512 thr. block = (b = bid&1, it = bid>>1) -> 4 output rows.
// thread = (o = tid&15 col-quad of v, js = tid>>4 j-slice of 32).
// Each thread accumulates g4[rr] (4 rows x 4 cols) over its 32 j's.
__global__ __launch_bounds__(512) void k_all(
    const float* __restrict__ inp, const float* __restrict__ kin,
    const float* __restrict__ vin, const float* __restrict__ W,
    const float* __restrict__ Wk,  const float* __restrict__ Wv,
    const float* __restrict__ a,   const float* __restrict__ adj,
    float* __restrict__ out)
{
    __shared__ float wk1[64], wk2[64];   // hi: Wk@a1, Wk@a2 ; lo: wk1 = W@(a1+a2)
    __shared__ float kflo[4][2];         // lo: per-row softmax weight by j-half
    __shared__ float e[512];             // hi: e[j], period-512
    __shared__ float zred[8];
    __shared__ float accred[8][4][64];   // per-wave g partials
    __shared__ float gred[4][64];        // final g per row

    const int tid  = threadIdx.x;
    const int b    = blockIdx.x & 1;
    const int it   = blockIdx.x >> 1;      // 0..255
    const bool hi  = (it >= 128);          // block-uniform
    const int o    = tid & 15;
    const int js   = tid >> 4;             // 0..31
    const int w    = tid >> 6;             // wave 0..7
    const int lane = tid & 63;
    const int i0   = it*4;

    // ---- phase 0: folded weight vectors (tiny) ----
    if (hi){
        if (tid < 128){
            int c = tid & 63;
            const float4* Wr = (const float4*)(Wk + c*32);
            const float4* av = (const float4*)(a + ((tid < 64) ? 0 : 32));
            float s = 0.f;
            #pragma unroll
            for (int q = 0; q < 8; q++){
                float4 wv = Wr[q]; float4 aq = av[q];
                s += wv.x*aq.x + wv.y*aq.y + wv.z*aq.z + wv.w*aq.w;
            }
            if (tid < 64) wk1[c] = s; else wk2[c] = s;
        }
    } else {
        if (tid < 64){
            const float4* Wr = (const float4*)(W + tid*32);
            const float4* a1 = (const float4*)(a);
            const float4* a2 = (const float4*)(a + 32);
            float s = 0.f;
            #pragma unroll
            for (int q = 0; q < 8; q++){
                float4 wv = Wr[q]; float4 x = a1[q]; float4 y = a2[q];
                s += wv.x*(x.x+y.x) + wv.y*(x.y+y.y) + wv.z*(x.z+y.z) + wv.w*(x.w+y.w);
            }
            wk1[tid] = s;
        }
    }
    __syncthreads();

    // ---- phase 1: per-block softmax prep ----
    float invZ = 0.f;
    if (hi){
        // e[t] for t=0..511 ; thread t: rows 2t (wk1), 2t+1 (wk2), no wrap.
        const float4* kr = (const float4*)(kin + b*65536 + (2*tid)*64);
        float q1 = 0.f, q2 = 0.f;
        #pragma unroll
        for (int q = 0; q < 16; q++){
            float4 k0 = kr[q];        // row 2t,   dword-quad q
            float4 k1 = kr[q+16];     // row 2t+1
            int c = q*4;
            q1 += k0.x*wk1[c] + k0.y*wk1[c+1] + k0.z*wk1[c+2] + k0.w*wk1[c+3];
            q2 += k1.x*wk2[c] + k1.y*wk2[c+1] + k1.z*wk2[c+2] + k1.w*wk2[c+3];
        }
        float ev = __expf(leaky(q1 + q2));
        e[tid] = ev;
        float zsum = ev;
        #pragma unroll
        for (int m = 32; m; m >>= 1) zsum += __shfl_xor(zsum, m);
        if (lane == 0) zred[w] = zsum;
        __syncthreads();
        float Z = 2.f*(zred[0]+zred[1]+zred[2]+zred[3]
                      +zred[4]+zred[5]+zred[6]+zred[7]);
        invZ = __frcp_rn(Z);
    } else {
        if (tid < 4){
            int r0 = (i0 + tid)*2;
            const float4* x0 = (const float4*)(inp + b*65536 + r0*64);
            float p0 = 0.f, p1 = 0.f;
            #pragma unroll
            for (int q = 0; q < 16; q++){
                float4 v0 = x0[q]; float4 v1 = x0[q+16];
                int c = q*4;
                p0 += v0.x*wk1[c] + v0.y*wk1[c+1] + v0.z*wk1[c+2] + v0.w*wk1[c+3];
                p1 += v1.x*wk1[c] + v1.y*wk1[c+1] + v1.z*wk1[c+2] + v1.w*wk1[c+3];
            }
            float e0 = __expf(leaky(p0)), e1 = __expf(leaky(p1));
            float d  = __frcp_rn(512.f*(e0 + e1));
            kflo[tid][0] = e0*d; kflo[tid][1] = e1*d;
        }
        __syncthreads();
    }

    float kf0=0.f, kf1=0.f, kf2=0.f, kf3=0.f;
    const int half = (js >= 16) ? 1 : 0;
    if (!hi){
        kf0 = kflo[0][half]; kf1 = kflo[1][half];
        kf2 = kflo[2][half]; kf3 = kflo[3][half];
    }

    // ---- phase 2: main loop  g[rr][cols] += (adj+w)·v over 32 j ----
    const int j0 = js*32;
    const float*  adjb = adj + i0*1024 + j0;
    const float*  vbp  = vin + b*65536 + j0*64 + o*4;
    const float4* ep   = (const float4*)(e + (j0 & 511));
    float4 g0 = make_float4(0.f,0.f,0.f,0.f);
    float4 g1 = make_float4(0.f,0.f,0.f,0.f);
    float4 g2 = make_float4(0.f,0.f,0.f,0.f);
    float4 g3 = make_float4(0.f,0.f,0.f,0.f);

    #pragma unroll 4
    for (int grp = 0; grp < 8; grp++){
        int jg = grp*4;
        float4 a0 = *(const float4*)(adjb + jg);
        float4 a1 = *(const float4*)(adjb + 1024 + jg);
        float4 a2 = *(const float4*)(adjb + 2048 + jg);
        float4 a3 = *(const float4*)(adjb + 3072 + jg);
        float4 v0 = *(const float4*)(vbp + (jg+0)*64);
        float4 v1 = *(const float4*)(vbp + (jg+1)*64);
        float4 v2 = *(const float4*)(vbp + (jg+2)*64);
        float4 v3 = *(const float4*)(vbp + (jg+3)*64);
        if (hi){
            float4 e4 = ep[grp];
            float w0 = e4.x*invZ, w1 = e4.y*invZ, w2 = e4.z*invZ, w3 = e4.w*invZ;
            float c0,c1,c2,c3;
            c0=a0.x+w0; c1=a0.y+w1; c2=a0.z+w2; c3=a0.w+w3;
            g0.x += c0*v0.x + c1*v1.x + c2*v2.x + c3*v3.x;
            g0.y += c0*v0.y + c1*v1.y + c2*v2.y + c3*v3.y;
            g0.z += c0*v0.z + c1*v1.z + c2*v2.z + c3*v3.z;
            g0.w += c0*v0.w + c1*v1.w + c2*v2.w + c3*v3.w;
            c0=a1.x+w0; c1=a1.y+w1; c2=a1.z+w2; c3=a1.w+w3;
            g1.x += c0*v0.x + c1*v1.x + c2*v2.x + c3*v3.x;
            g1.y += c0*v0.y + c1*v1.y + c2*v2.y + c3*v3.y;
            g1.z += c0*v0.z + c1*v1.z + c2*v2.z + c3*v3.z;
            g1.w += c0*v0.w + c1*v1.w + c2*v2.w + c3*v3.w;
            c0=a2.x+w0; c1=a2.y+w1; c2=a2.z+w2; c3=a2.w+w3;
            g2.x += c0*v0.x + c1*v1.x + c2*v2.x + c3*v3.x;
            g2.y += c0*v0.y + c1*v1.y + c2*v2.y + c3*v3.y;
            g2.z += c0*v0.z + c1*v1.z + c2*v2.z + c3*v3.z;
            g2.w += c0*v0.w + c1*v1.w + c2*v2.w + c3*v3.w;
            c0=a3.x+w0; c1=a3.y+w1; c2=a3.z+w2; c3=a3.w+w3;
            g3.x += c0*v0.x + c1*v1.x + c2*v2.x + c3*v3.x;
            g3.y += c0*v0.y + c1*v1.y + c2*v2.y + c3*v3.y;
            g3.z += c0*v0.z + c1*v1.z + c2*v2.z + c3*v3.z;
            g3.w += c0*v0.w + c1*v1.w + c2*v2.w + c3*v3.w;
        } else {
            float c0,c1,c2,c3;
            c0=a0.x+kf0; c1=a0.y+kf0; c2=a0.z+kf0; c3=a0.w+kf0;
            g0.x += c0*v0.x + c1*v1.x + c2*v2.x + c3*v3.x;
            g0.y += c0*v0.y + c1*v1.y + c2*v2.y + c3*v3.y;
            g0.z += c0*v0.z + c1*v1.z + c2*v2.z + c3*v3.z;
            g0.w += c0*v0.w + c1*v1.w + c2*v2.w + c3*v3.w;
            c0=a1.x+kf1; c1=a1.y+kf1; c2=a1.z+kf1; c3=a1.w+kf1;
            g1.x += c0*v0.x + c1*v1.x + c2*v2.x + c3*v3.x;
            g1.y += c0*v0.y + c1*v1.y + c2*v2.y + c3*v3.y;
            g1.z += c0*v0.z + c1*v1.z + c2*v2.z + c3*v3.z;
            g1.w += c0*v0.w + c1*v1.w + c2*v2.w + c3*v3.w;
            c0=a2.x+kf2; c1=a2.y+kf2; c2=a2.z+kf2; c3=a2.w+kf2;
            g2.x += c0*v0.x + c1*v1.x + c2*v2.x + c3*v3.x;
            g2.y += c0*v0.y + c1*v1.y + c2*v2.y + c3*v3.y;
            g2.z += c0*v0.z + c1*v1.z + c2*v2.z + c3*v3.z;
            g2.w += c0*v0.w + c1*v1.w + c2*v2.w + c3*v3.w;
            c0=a3.x+kf3; c1=a3.y+kf3; c2=a3.z+kf3; c3=a3.w+kf3;
            g3.x += c0*v0.x + c1*v1.x + c2*v2.x + c3*v3.x;
            g3.y += c0*v0.y + c1*v1.y + c2*v2.y + c3*v3.y;
            g3.z += c0*v0.z + c1*v1.z + c2*v2.z + c3*v3.z;
            g3.w += c0*v0.w + c1*v1.w + c2*v2.w + c3*v3.w;
        }
    }

    // ---- reduce g over the 4 js-slices within each wave (lane bits 4,5) ----
    #define RED2(x) { x += __shfl_xor(x,16); x += __shfl_xor(x,32); }
    RED2(g0.x) RED2(g0.y) RED2(g0.z) RED2(g0.w)
    RED2(g1.x) RED2(g1.y) RED2(g1.z) RED2(g1.w)
    RED2(g2.x) RED2(g2.y) RED2(g2.z) RED2(g2.w)
    RED2(g3.x) RED2(g3.y) RED2(g3.z) RED2(g3.w)
    #undef RED2
    if ((lane & 48) == 0){   // lane < 16
        *(float4*)&accred[w][0][o*4] = g0;
        *(float4*)&accred[w][1][o*4] = g1;
        *(float4*)&accred[w][2][o*4] = g2;
        *(float4*)&accred[w][3][o*4] = g3;
    }
    __syncthreads();

    // ---- reduce across waves -> gred[4][64] ----
    if (tid < 256){
        int rr = tid >> 6, c = tid & 63;
        gred[rr][c] = accred[0][rr][c] + accred[1][rr][c]
                    + accred[2][rr][c] + accred[3][rr][c]
                    + accred[4][rr][c] + accred[5][rr][c]
                    + accred[6][rr][c] + accred[7][rr][c];
    }
    __syncthreads();

    // ---- epilogue: out[i][f] = leaky(0.5 * g[rr]·Wv[:,f]) ----
    if (tid < 128){
        int rr = tid >> 5, f = tid & 31;
        const float* gr = gred[rr];
        float s0=0.f, s1=0.f, s2=0.f, s3=0.f;
        #pragma unroll
        for (int c = 0; c < 64; c += 4){
            s0 += gr[c+0]*Wv[(c+0)*32 + f];
            s1 += gr[c+1]*Wv[(c+1)*32 + f];
            s2 += gr[c+2]*Wv[(c+2)*32 + f];
            s3 += gr[c+3]*Wv[(c+3)*32 + f];
        }
        out[(b*1024 + i0 + rr)*32 + f] = leaky(0.5f*((s0+s1)+(s2+s3)));
    }
}

extern "C" void kernel_launch(void* const* d_in, const int* in_sizes, int n_in,
                              void* d_out, int out_size, void* d_ws, size_t ws_size,
                              hipStream_t stream)
{
    const float* inp = (const float*)d_in[0];
    const float* kin = (const float*)d_in[1];
    const float* vin = (const float*)d_in[2];
    const float* adj = (const float*)d_in[3];
    const float* W   = (const float*)d_in[4];
    const float* Wk  = (const float*)d_in[5];
    const float* Wv  = (const float*)d_in[6];
    const float* a   = (const float*)d_in[7];
    float* out = (float*)d_out;
    (void)in_sizes; (void)n_in; (void)out_size; (void)d_ws; (void)ws_size;

    hipLaunchKernelGGL(k_all, dim3(512), dim3(512), 0, stream,
                       inp, kin, vin, W, Wk, Wv, a, adj, out);
}

// Round 5
// 85.337 us; speedup vs baseline: 1.1211x; 1.1211x over previous
//
#include <hip/hip_runtime.h>

// B=2, N=1024, Fin=64, Fout=32 — all fp32.
// Degenerate-score GAT, 2 kernels (round-10: REVERT to round-8 best, 84.4us).
//   K1 k_proj : projections -> vv (j-major [b][j][f]), p, q1, q2.
//               float4 input loads (96 -> 24 VMEM instrs/wave).
//   K2 k_fused: SINGLE-accumulator main loop. att is folded into the adj
//     dot: coeff_j = adj[i][j] + e[j]*invZ (hi) / adj[i][j] + kf (lo).
// Session budget model (measured r0-r4):
//   dur ~= 41us fill (harness re-poison, fixed)
//        + ~24us graph/dispatch fixed cost (node-count-INSENSITIVE: r4's
//          1-node variant was +11us despite one fewer boundary)
//        + ~19us kernel bodies (latency-bound: VALUBusy 3.5% measured r1;
//          2x occupancy bought 1.2us; -37% main-loop VALU bought 1.4us).
// Dead ends (measured): grid-wide sync fusion ~50-65us (r1); algebraic
// 1-kernel fusion +11us (r4). Do not revisit.

#define ALPHA 0.01f

__device__ __forceinline__ float leaky(float x){ return x >= 0.f ? x : ALPHA*x; }

// ---------------- K1: projections + row scalars -------------------------
// 512 blocks x 256 thr; 4 rows/block; wave = 1 row; lane-halves split c.
__global__ __launch_bounds__(256) void k_proj(
    const float* __restrict__ inp, const float* __restrict__ kin,
    const float* __restrict__ vin, const float* __restrict__ W,
    const float* __restrict__ Wk,  const float* __restrict__ Wv,
    const float* __restrict__ a,
    float* __restrict__ vv, float* __restrict__ p,
    float* __restrict__ q1, float* __restrict__ q2)
{
    int tid  = threadIdx.x;
    int lane = tid & 63;
    int f    = lane & 31;
    int h    = lane >> 5;          // c-half selector
    int rl   = tid >> 6;           // 0..3
    int row  = blockIdx.x*4 + rl;  // 0..2047
    const float4* xr4 = (const float4*)(inp + row*64 + h*32);
    const float4* kr4 = (const float4*)(kin + row*64 + h*32);
    const float4* vr4 = (const float4*)(vin + row*64 + h*32);
    const float* Wb  = W  + (h*32)*32 + f;
    const float* Wkb = Wk + (h*32)*32 + f;
    const float* Wvb = Wv + (h*32)*32 + f;
    float ha = 0.f, ka = 0.f, va = 0.f;
    #pragma unroll
    for (int cc = 0; cc < 8; cc++){
        float4 xv = xr4[cc];
        float4 kv = kr4[cc];
        float4 v4 = vr4[cc];
        int c0 = cc*4;
        ha += xv.x*Wb [(c0+0)*32] + xv.y*Wb [(c0+1)*32]
            + xv.z*Wb [(c0+2)*32] + xv.w*Wb [(c0+3)*32];
        ka += kv.x*Wkb[(c0+0)*32] + kv.y*Wkb[(c0+1)*32]
            + kv.z*Wkb[(c0+2)*32] + kv.w*Wkb[(c0+3)*32];
        va += v4.x*Wvb[(c0+0)*32] + v4.y*Wvb[(c0+1)*32]
            + v4.z*Wvb[(c0+2)*32] + v4.w*Wvb[(c0+3)*32];
    }
    ha += __shfl_xor(ha, 32);
    ka += __shfl_xor(ka, 32);
    va += __shfl_xor(va, 32);
    if (h == 0) vv[row*32 + f] = va;        // j-major layout
    float a1 = a[f], a2 = a[32+f];
    float pv  = ha*(a1+a2);
    float q1v = ka*a1;
    float q2v = ka*a2;
    #pragma unroll
    for (int m = 16; m; m >>= 1){
        pv  += __shfl_xor(pv , m);
        q1v += __shfl_xor(q1v, m);
        q2v += __shfl_xor(q2v, m);
    }
    if (lane == 0){ p[row] = pv; q1[row] = q1v; q2[row] = q2v; }
}

// ---------------- K2: folded softmax + adj@vv + epilogue ----------------
// 512 blocks x 512 thr. block = (batch b, 4 rows). thread = (o, rr, js):
//   o  = tid&7        feature quad (f = o*4..o*4+3)
//   rr = (tid>>3)&3   row within block
//   js = tid>>5       j-slice of 64 (waves 0-3: j<512, waves 4-7: j>=512)
// Single accumulator: coeff_j = adj[i][j] + (softmax weight for j), with
// the softmax weight fully resolvable BEFORE the main loop:
//   lo (it<128) : kf = e{0,1}/(512(e0+e1)) from own-row p — no staging
//   hi (it>=128): e[j]*invZ with e,Z staged once per block
__global__ __launch_bounds__(512) void k_fused(
    const float* __restrict__ adj, const float* __restrict__ vv,
    const float* __restrict__ p,   const float* __restrict__ q1,
    const float* __restrict__ q2,  float* __restrict__ out)
{
    __shared__ float e[1024];            // hi-blocks only
    __shared__ float accred[8][4][32];   // [wave][row][feature]
    __shared__ float zred[8];            // hi-blocks only

    int tid = threadIdx.x;
    int b   = blockIdx.x & 1;
    int it  = blockIdx.x >> 1;        // 0..255
    int o   = tid & 7;
    int rr  = (tid >> 3) & 3;
    int js  = tid >> 5;               // 0..15
    int w   = tid >> 6;               // wave 0..7
    int i   = it*4 + rr;
    bool hi = (it >= 128);            // block-uniform: rows i >= 512

    const float4* ap = (const float4*)(adj + i*1024 + js*64);
    const float*  vb = vv + b*32768 + js*64*32 + o*4;
    float4 acc = make_float4(0.f,0.f,0.f,0.f);

    if (hi){
        // prefetch first adj chunk: overlap HBM latency with e-staging
        float4 pre0 = ap[0];
        float4 pre1 = ap[1];

        // ---- stage e[1024] + Z (scores ~|2|, exp w/o max-sub safe) ----
        const float* q1b = q1 + b*1024;
        const float* q2b = q2 + b*1024;
        float zsum = 0.f;
        #pragma unroll
        for (int t = 0; t < 2; t++){
            int j  = tid*2 + t;
            float s = leaky(q1b[(2*j) & 1023] + q2b[(2*j+1) & 1023]);
            float ev = __expf(s);
            e[j] = ev;
            zsum += ev;
        }
        #pragma unroll
        for (int m = 32; m; m >>= 1) zsum += __shfl_xor(zsum, m);
        if ((tid & 63) == 0) zred[w] = zsum;
        __syncthreads();

        float Z = zred[0] + zred[1] + zred[2] + zred[3]
                + zred[4] + zred[5] + zred[6] + zred[7];
        float invZ = __frcp_rn(Z);

        const float4* ep = (const float4*)(e + js*64);
        #pragma unroll 4
        for (int m = 0; m < 16; m++){
            float4 a4 = (m == 0) ? pre0 : (m == 1) ? pre1 : ap[m];
            float4 e4 = ep[m];
            const float* v0p = vb + m*128;
            float4 v0 = *(const float4*)(v0p);
            float4 v1 = *(const float4*)(v0p + 32);
            float4 v2 = *(const float4*)(v0p + 64);
            float4 v3 = *(const float4*)(v0p + 96);
            float c0 = fmaf(e4.x, invZ, a4.x);
            float c1 = fmaf(e4.y, invZ, a4.y);
            float c2 = fmaf(e4.z, invZ, a4.z);
            float c3 = fmaf(e4.w, invZ, a4.w);
            acc.x += c0*v0.x; acc.y += c0*v0.y; acc.z += c0*v0.z; acc.w += c0*v0.w;
            acc.x += c1*v1.x; acc.y += c1*v1.y; acc.z += c1*v1.z; acc.w += c1*v1.w;
            acc.x += c2*v2.x; acc.y += c2*v2.y; acc.z += c2*v2.z; acc.w += c2*v2.w;
            acc.x += c3*v3.x; acc.y += c3*v3.y; acc.z += c3*v3.z; acc.w += c3*v3.w;
        }
    } else {
        // ---- lo: softmax weight from own-row p, uniform per j-half ----
        float s0 = leaky(p[b*1024 + 2*i]);
        float s1 = leaky(p[b*1024 + 2*i + 1]);
        float e0 = __expf(s0), e1 = __expf(s1);
        float kf = ((js < 8) ? e0 : e1) / (512.f*(e0 + e1));
        #pragma unroll 4
        for (int m = 0; m < 16; m++){
            float4 a4 = ap[m];
            const float* v0p = vb + m*128;
            float4 v0 = *(const float4*)(v0p);
            float4 v1 = *(const float4*)(v0p + 32);
            float4 v2 = *(const float4*)(v0p + 64);
            float4 v3 = *(const float4*)(v0p + 96);
            float c0 = a4.x + kf;
            float c1 = a4.y + kf;
            float c2 = a4.z + kf;
            float c3 = a4.w + kf;
            acc.x += c0*v0.x; acc.y += c0*v0.y; acc.z += c0*v0.z; acc.w += c0*v0.w;
            acc.x += c1*v1.x; acc.y += c1*v1.y; acc.z += c1*v1.z; acc.w += c1*v1.w;
            acc.x += c2*v2.x; acc.y += c2*v2.y; acc.z += c2*v2.z; acc.w += c2*v2.w;
            acc.x += c3*v3.x; acc.y += c3*v3.y; acc.z += c3*v3.z; acc.w += c3*v3.w;
        }
    }

    // combine js pairs within wave (lane ^ 32)
    acc.x += __shfl_xor(acc.x, 32); acc.y += __shfl_xor(acc.y, 32);
    acc.z += __shfl_xor(acc.z, 32); acc.w += __shfl_xor(acc.w, 32);
    if ((tid & 32) == 0){
        accred[w][rr][o*4+0] = acc.x;
        accred[w][rr][o*4+1] = acc.y;
        accred[w][rr][o*4+2] = acc.z;
        accred[w][rr][o*4+3] = acc.w;
    }
    __syncthreads();

    // ---- epilogue: 128 threads = (row rr2, feature f) ----
    if (tid < 128){
        int rr2 = tid >> 5, f = tid & 31;
        float accsum = accred[0][rr2][f] + accred[1][rr2][f]
                     + accred[2][rr2][f] + accred[3][rr2][f]
                     + accred[4][rr2][f] + accred[5][rr2][f]
                     + accred[6][rr2][f] + accred[7][rr2][f];
        int i2 = it*4 + rr2;
        out[(b*1024 + i2)*32 + f] = leaky(0.5f*accsum);
    }
}

extern "C" void kernel_launch(void* const* d_in, const int* in_sizes, int n_in,
                              void* d_out, int out_size, void* d_ws, size_t ws_size,
                              hipStream_t stream)
{
    const float* inp = (const float*)d_in[0];
    const float* kin = (const float*)d_in[1];
    const float* vin = (const float*)d_in[2];
    const float* adj = (const float*)d_in[3];
    const float* W   = (const float*)d_in[4];
    const float* Wk  = (const float*)d_in[5];
    const float* Wv  = (const float*)d_in[6];
    const float* a   = (const float*)d_in[7];
    float* out = (float*)d_out;

    float* ws  = (float*)d_ws;
    float* vv  = ws;            // 65536 floats, [b][j][f]
    float* p   = ws + 65536;    // 2048
    float* q1  = ws + 67584;    // 2048
    float* q2  = ws + 69632;    // 2048
    (void)in_sizes; (void)n_in; (void)out_size; (void)ws_size;

    hipLaunchKernelGGL(k_proj, dim3(512), dim3(256), 0, stream,
                       inp, kin, vin, W, Wk, Wv, a, vv, p, q1, q2);
    hipLaunchKernelGGL(k_fused, dim3(512), dim3(512), 0, stream,
                       adj, vv, p, q1, q2, out);
}